// Round 13
// baseline (1713.752 us; speedup 1.0000x reference)
//
#include <hip/hip_runtime.h>
#include <hip/hip_bf16.h>

typedef short s16x8 __attribute__((ext_vector_type(8)));
typedef float f32x4 __attribute__((ext_vector_type(4)));
typedef unsigned short u16;
typedef unsigned short u16x4 __attribute__((ext_vector_type(4)));
typedef unsigned long long u64;
typedef unsigned long long u64x2 __attribute__((ext_vector_type(2)));

__device__ __forceinline__ u16 f2bf(float f) {
  __hip_bfloat16 h = __float2bfloat16(f);
  u16 u;
  __builtin_memcpy(&u, &h, sizeof(u));
  return u;
}
__device__ __forceinline__ float bf2f(u16 u) {
  unsigned int x = ((unsigned int)u) << 16;
  float f;
  __builtin_memcpy(&f, &x, 4);
  return f;
}

// device-scope relaxed atomics (serviced at L3 coherence point; no fences)
__device__ __forceinline__ unsigned int a_ld32(const unsigned int* p) {
  return __hip_atomic_load(p, __ATOMIC_RELAXED, __HIP_MEMORY_SCOPE_AGENT);
}
__device__ __forceinline__ u64 a_ld64(const u64* p) {
  return __hip_atomic_load(p, __ATOMIC_RELAXED, __HIP_MEMORY_SCOPE_AGENT);
}
__device__ __forceinline__ void a_st32(unsigned int* p, unsigned int v) {
  __hip_atomic_store(p, v, __ATOMIC_RELAXED, __HIP_MEMORY_SCOPE_AGENT);
}

// async global->LDS, 16B per lane; lds addr must be wave-uniform base
__device__ __forceinline__ void gload16(const void* g, void* l) {
  __builtin_amdgcn_global_load_lds(
      (const __attribute__((address_space(1))) unsigned int*)g,
      (__attribute__((address_space(3))) unsigned int*)l, 16, 0, 0);
}

// ---------------------------------------------------------------------------
// Generic bf16 MFMA GEMM:  C[m,n] = act( sum_k A[m,k]*B[n,k] + bias[n] )
// 128x128 tile, BK=32, 256 threads. Staging via global_load_lds width-16.
// z-batched; per-z overrides (ids2/bias2/dM). SWAPXY: M-tiles on blockIdx.x.
// STATS: epilogue reduces each 128x128 C-tile to per-row (max, sumexp)
// partials for a downstream fused log-softmax (pmax/psum: [M][gridN]).
// ---------------------------------------------------------------------------
template<int CBF16, int GATHER, int TANHA, int BIAS, int SWAPXY, int STATS>
__global__ __launch_bounds__(256) void gemm_bt(
    const u16* __restrict__ A, const u16* __restrict__ B,
    const float* __restrict__ bias, void* __restrict__ Cv,
    const int* __restrict__ ids,
    int M, int N, int K, int lda, int ldb, int ldc,
    long sAz, long sBz, long sCz, int rpb, long cbs,
    const int* __restrict__ ids2, const float* __restrict__ bias2, int dM,
    float* __restrict__ pmax, float* __restrict__ psum)
{
  __shared__ u16 sA[4096];
  __shared__ u16 sB[4096];
  __shared__ float sstat[128][2][2];
  const int tid = threadIdx.x;
  const int z = blockIdx.z;
  if (z) {
    if (dM) M += dM;
    if (ids2) ids = ids2;
    if (bias2) bias = bias2;
  }
  const int m0 = (SWAPXY ? blockIdx.x : blockIdx.y) * 128;
  const int n0 = (SWAPXY ? blockIdx.y : blockIdx.x) * 128;
  const int nt = (SWAPXY ? blockIdx.y : blockIdx.x);
  const int gridN = (SWAPXY ? gridDim.y : gridDim.x);
  const u16* Ab = A + z * sAz;
  const u16* Bb = B + z * sBz;
  const int w = tid >> 6, lane = tid & 63;
  const int wr = w >> 1, wc = w & 1;
  const int lr = lane & 15, lk = lane >> 4;
  f32x4 acc[4][4] = {};
  const int e0 = tid * 8, e1 = e0 + 2048;
  const int r0 = e0 >> 5, c0 = e0 & 31;
  const int r1 = e1 >> 5, c1 = e1 & 31;
  long arow0, arow1;
  if (GATHER) {
    int i0 = m0 + r0; if (i0 >= M) i0 = M - 1;
    int i1 = m0 + r1; if (i1 >= M) i1 = M - 1;
    arow0 = (long)ids[i0] * lda;
    arow1 = (long)ids[i1] * lda;
  } else {
    arow0 = (long)(m0 + r0) * lda;
    arow1 = (long)(m0 + r1) * lda;
  }
  const long brow0 = (long)(n0 + r0) * ldb;
  const long brow1 = (long)(n0 + r1) * ldb;
  char* sAc = (char*)sA;
  char* sBc = (char*)sB;
  const size_t cb = (size_t)w * 1024;
  for (int kt = 0; kt < K; kt += 32) {
    __syncthreads();
    gload16(Ab + arow0 + kt + c0, sAc + cb);
    gload16(Ab + arow1 + kt + c1, sAc + 4096 + cb);
    gload16(Bb + brow0 + kt + c0, sBc + cb);
    gload16(Bb + brow1 + kt + c1, sBc + 4096 + cb);
    __syncthreads();
    s16x8 af[4], bf[4];
#pragma unroll
    for (int i = 0; i < 4; i++) {
      af[i] = *(const s16x8*)&sA[(wr*64 + i*16 + lr)*32 + lk*8];
      bf[i] = *(const s16x8*)&sB[(wc*64 + i*16 + lr)*32 + lk*8];
    }
#pragma unroll
    for (int mi = 0; mi < 4; mi++)
#pragma unroll
      for (int ni = 0; ni < 4; ni++)
        acc[mi][ni] = __builtin_amdgcn_mfma_f32_16x16x32_bf16(af[mi], bf[ni], acc[mi][ni], 0, 0, 0);
  }
#pragma unroll
  for (int mi = 0; mi < 4; mi++) {
#pragma unroll
    for (int ni = 0; ni < 4; ni++) {
#pragma unroll
      for (int r = 0; r < 4; r++) {
        int gm = m0 + wr*64 + mi*16 + lk*4 + r;
        int gn = n0 + wc*64 + ni*16 + lr;
        if (gm < M && gn < N) {
          float v = acc[mi][ni][r];
          if (BIAS) v += bias[gn];
          if (TANHA) v = tanhf(v);
          long ci = z * sCz + (long)(gm / rpb) * cbs + (long)(gm % rpb) * ldc + gn;
          if (CBF16) ((u16*)Cv)[ci] = f2bf(v);
          else       ((float*)Cv)[ci] = v;
        }
      }
    }
  }
  if (STATS) {
    // per-row (max, sumexp) over this WG's 128-col tile
#pragma unroll
    for (int mi = 0; mi < 4; mi++) {
#pragma unroll
      for (int r = 0; r < 4; r++) {
        float m = -1e30f, s = 0.f;
#pragma unroll
        for (int ni = 0; ni < 4; ni++) {
          int gn = n0 + wc*64 + ni*16 + lr;
          if (gn < N) {
            float v = acc[mi][ni][r];
            if (BIAS) v += bias[gn];
            m = fmaxf(m, v);
          }
        }
#pragma unroll
        for (int ni = 0; ni < 4; ni++) {
          int gn = n0 + wc*64 + ni*16 + lr;
          if (gn < N) {
            float v = acc[mi][ni][r];
            if (BIAS) v += bias[gn];
            s += expf(v - m);
          }
        }
#pragma unroll
        for (int off = 1; off < 16; off <<= 1) {
          float mo = __shfl_xor(m, off), so = __shfl_xor(s, off);
          float nm = fmaxf(m, mo);
          s = s * expf(m - nm) + so * expf(mo - nm);
          m = nm;
        }
        if (lr == 0) {
          int row = wr*64 + mi*16 + lk*4 + r;
          sstat[row][wc][0] = m;
          sstat[row][wc][1] = s;
        }
      }
    }
    __syncthreads();
    if (tid < 128) {
      int gm = m0 + tid;
      if (gm < M) {
        float ma = sstat[tid][0][0], sa = sstat[tid][0][1];
        float mb = sstat[tid][1][0], sb = sstat[tid][1][1];
        float nm = fmaxf(ma, mb);
        float s = sa * expf(ma - nm) + sb * expf(mb - nm);
        pmax[(long)gm * gridN + nt] = nm;
        psum[(long)gm * gridN + nt] = s;
      }
    }
  }
}

// ---------------------------------------------------------------------------
// MLP GEMM with fused feature-concat A-gather (proven R11/R12).
// ---------------------------------------------------------------------------
__global__ __launch_bounds__(256) void gemm_mlp(
    const u16* __restrict__ oute, const u16* __restrict__ ctxp,
    const u16* __restrict__ encp, const u16* __restrict__ outw,
    const int* __restrict__ ki_bt, const int* __restrict__ an_bt,
    const u16* __restrict__ B, const float* __restrict__ bias,
    u16* __restrict__ C)
{
  __shared__ u16 sA[4096];
  __shared__ u16 sB[4096];
  const int tid = threadIdx.x;
  const int m0 = blockIdx.y * 128, n0 = blockIdx.x * 128;
  const int w = tid >> 6, lane = tid & 63;
  const int wr = w >> 1, wc = w & 1;
  const int lr = lane & 15, lk = lane >> 4;
  f32x4 acc[4][4] = {};
  const int e0 = tid * 8, e1 = e0 + 2048;
  const int r0 = e0 >> 5, c0 = e0 & 31;
  const int r1 = e1 >> 5, c1 = e1 & 31;
  const u16 *b00, *b01, *b02, *b03, *b10, *b11, *b12, *b13;
  {
    int m = m0 + r0; if (m >= 2040) m = 2039;
    int b = m / 255, t = m - b * 255;
    b00 = oute + ((long)(b * 256 + t)) * 768;
    b01 = ctxp + ((long)(b * 256 + t)) * 768;
    b02 = encp + ((long)(b * 384 + an_bt[m])) * 768;
    b03 = outw + ((long)(b * 256 + ki_bt[m])) * 768;
    m = m0 + r1; if (m >= 2040) m = 2039;
    b = m / 255; t = m - b * 255;
    b10 = oute + ((long)(b * 256 + t)) * 768;
    b11 = ctxp + ((long)(b * 256 + t)) * 768;
    b12 = encp + ((long)(b * 384 + an_bt[m])) * 768;
    b13 = outw + ((long)(b * 256 + ki_bt[m])) * 768;
  }
  const long brow0 = (long)(n0 + r0) * 3072;
  const long brow1 = (long)(n0 + r1) * 3072;
  char* sAc = (char*)sA;
  char* sBc = (char*)sB;
  const size_t cb = (size_t)w * 1024;
  for (int kt = 0; kt < 3072; kt += 32) {
    const int seg = kt / 768, off = kt - seg * 768;
    const u16* a0 = (seg == 0 ? b00 : seg == 1 ? b01 : seg == 2 ? b02 : b03) + off + c0;
    const u16* a1 = (seg == 0 ? b10 : seg == 1 ? b11 : seg == 2 ? b12 : b13) + off + c1;
    __syncthreads();
    gload16(a0, sAc + cb);
    gload16(a1, sAc + 4096 + cb);
    gload16(B + brow0 + kt + c0, sBc + cb);
    gload16(B + brow1 + kt + c1, sBc + 4096 + cb);
    __syncthreads();
    s16x8 af[4], bf[4];
#pragma unroll
    for (int i = 0; i < 4; i++) {
      af[i] = *(const s16x8*)&sA[(wr*64 + i*16 + lr)*32 + lk*8];
      bf[i] = *(const s16x8*)&sB[(wc*64 + i*16 + lr)*32 + lk*8];
    }
#pragma unroll
    for (int mi = 0; mi < 4; mi++)
#pragma unroll
      for (int ni = 0; ni < 4; ni++)
        acc[mi][ni] = __builtin_amdgcn_mfma_f32_16x16x32_bf16(af[mi], bf[ni], acc[mi][ni], 0, 0, 0);
  }
#pragma unroll
  for (int mi = 0; mi < 4; mi++) {
#pragma unroll
    for (int ni = 0; ni < 4; ni++) {
#pragma unroll
      for (int r = 0; r < 4; r++) {
        int gm = m0 + wr*64 + mi*16 + lk*4 + r;
        int gn = n0 + wc*64 + ni*16 + lr;
        if (gm < 2040 && gn < 768) {
          float v = tanhf(acc[mi][ni][r] + bias[gn]);
          C[(long)gm * 768 + gn] = f2bf(v);
        }
      }
    }
  }
}

// ---------------------------------------------------------------------------
// Pre-LSTM casts + gathered-emb cast + counter recurrence + tag zeroing.
// ---------------------------------------------------------------------------
__global__ __launch_bounds__(256) void cast_pre(
    const float* __restrict__ emb,
    const float* __restrict__ Wihe, u16* __restrict__ Wihe_bf,
    const float* __restrict__ Wihw, u16* __restrict__ Wihw_bf,
    const float* __restrict__ Walign, u16* __restrict__ Walign_bf,
    const float* __restrict__ encoder, u16* __restrict__ encd_bf,
    u16* __restrict__ gath_bf,
    const int* __restrict__ input_edits, const int* __restrict__ simp_sent,
    const int* __restrict__ org_ids,
    int* __restrict__ ki_bt, int* __restrict__ an_bt,
    unsigned int* __restrict__ tags)
{
  int r = blockIdx.x;
  if (r == 13312) {
    int b = threadIdx.x;
    tags[b] = 0;
    if (b >= 8) return;
    int kd = 0, ki = 0, an = 0;
    for (int t = 0; t < 255; t++) {
      int a = input_edits[b * 256 + t + 1];
      ki_bt[b * 255 + t] = ki;
      an_bt[b * 255 + t] = an;
      int kd2 = kd + ((a == 1) || (a == 2) ? 1 : 0);
      int ns = (a != 2) && (a != 102) && (a != 0);
      int ki2 = ki + (ns ? 1 : 0);
      int is_ins = ns && (a != 1);
      int nia = (org_ids[b * 257 + an + 1] == 103);
      int mx = (kd2 > an) ? kd2 : an;
      int an2 = (is_ins && nia) ? (an + 1) : mx;
      kd = kd2; ki = ki2; an = an2;
    }
    return;
  }
  const float* src; u16* dst; int valid, cols;
  if (r < 3072)                   { src=Wihe + (long)r*768;   dst=Wihe_bf + (long)r*768;   valid=1; cols=768; }
  else if ((r -= 3072) < 3072)    { src=Wihw + (long)r*768;   dst=Wihw_bf + (long)r*768;   valid=1; cols=768; }
  else if ((r -= 3072) < 768)     { src=Walign + (long)r*768; dst=Walign_bf + (long)r*768; valid=1; cols=768; }
  else if ((r -= 768) < 2176)     { src=encoder + (long)r*768; dst=encd_bf + (long)r*768;  valid=(r<2056); cols=768; }
  else if ((r -= 2176) < 2048)    { src=emb + (long)input_edits[r]*768; dst=gath_bf + (long)r*768; valid=1; cols=768; }
  else { r -= 2048;                 int ok=(r<2056);
                                    src=emb + (ok ? (long)simp_sent[r]*768 : 0); 
                                    dst=gath_bf + (long)(2048+r)*768; valid=ok; cols=768; }
  for (int c = threadIdx.x; c < cols; c += 256) {
    float v = valid ? src[c] : 0.f;
    dst[c] = f2bf(v);
  }
}

// ---------------------------------------------------------------------------
// Persistent LSTM (R6/R9 proven structure) + SHADOW WGs (R10).
// ---------------------------------------------------------------------------
__global__ __launch_bounds__(256, 1) void lstm_persist(
    const float* __restrict__ Whh_e, const float* __restrict__ Whh_w,
    const float* __restrict__ xW_e, const float* __restrict__ xW_w,
    const float* __restrict__ h0, const float* __restrict__ c0,
    u16* __restrict__ hglob, unsigned int* __restrict__ tags,
    u16* __restrict__ out_e, u16* __restrict__ out_w,
    float* __restrict__ out_tail,
    const float* __restrict__ Wout, u16* __restrict__ Wout_bf,
    const float* __restrict__ Wmlp, u16* __restrict__ Wmlp_bf,
    const float* __restrict__ Wattn, u16* __restrict__ Wattn_bf,
    const u16* __restrict__ enc_bf, u16* __restrict__ encT_bf)
{
  const int wg = blockIdx.x;
  const int tid = threadIdx.x;

  __shared__ u16 ldsh[12288];
  __shared__ float Gbuf[16][4][2][16];

  if (wg >= 48) {
    // ================= SHADOW PATH =================
    const int swg = wg - 48;
    u16 (*tile)[33] = (u16(*)[33])ldsh;
    const int TOT = 21248 + 768 + 768 + 1728;
    for (int u = swg; u < TOT; u += 208) {
      if (u < 21248) {
        const float* src = Wout + (long)u * 768;
        u16* dst = Wout_bf + (long)u * 768;
        bool ok = (u < 21128);
        for (int c = tid; c < 768; c += 256)
          dst[c] = f2bf(ok ? src[c] : 0.f);
      } else if (u < 22016) {
        int r = u - 21248;
        const float* src = Wmlp + (long)r * 3072;
        u16* dst = Wmlp_bf + (long)r * 3072;
        for (int c = tid; c < 3072; c += 256)
          dst[c] = f2bf(src[c]);
      } else if (u < 22784) {
        int r = u - 22016;
        const float* src = Wattn + (long)r * 768;
        u16* dst = Wattn_bf + (long)r * 768;
        for (int c = tid; c < 768; c += 256)
          dst[c] = f2bf(src[c]);
      } else {
        int tau = u - 22784;
        int s0 = (tau % 9) * 32;
        int rem = tau / 9;
        int hh0 = (rem % 24) * 32;
        int b = rem / 24;
        const int tx = tid & 31, ty = tid >> 5;
#pragma unroll
        for (int i = 0; i < 32; i += 8) {
          int s = s0 + ty + i;
          u16 v = (s < 257) ? enc_bf[((long)b * 384 + s) * 768 + hh0 + tx] : (u16)0;
          tile[ty + i][tx] = v;
        }
        __syncthreads();
#pragma unroll
        for (int i = 0; i < 32; i += 8) {
          int h = hh0 + ty + i;
          encT_bf[((long)b * 768 + h) * 288 + s0 + tx] = tile[tx][ty + i];
        }
        __syncthreads();
      }
    }
    return;
  }

  // ================= SYNC PATH (exact R9) =================
  const int l = wg / 24, grp = wg % 24;
  const int u0 = grp * 32;
  const int w = tid >> 6, lane = tid & 63;
  const int c16 = lane & 15, half = lane >> 4;
  const int uh = w >> 1, g0 = (w & 1) * 2;

  s16x8 wfrag[2][24];
  {
    const float* Wbase = l ? Whh_w : Whh_e;
#pragma unroll
    for (int g = 0; g < 2; g++) {
      const float* Wsrc = Wbase + (long)((g0 + g) * 768 + u0 + uh * 16 + c16) * 768 + half * 8;
#pragma unroll
      for (int s = 0; s < 24; s++) {
        float4 f0 = *(const float4*)(Wsrc + s * 32);
        float4 f1 = *(const float4*)(Wsrc + s * 32 + 4);
        s16x8 v;
        v[0]=f2bf(f0.x); v[1]=f2bf(f0.y); v[2]=f2bf(f0.z); v[3]=f2bf(f0.w);
        v[4]=f2bf(f1.x); v[5]=f2bf(f1.y); v[6]=f2bf(f1.z); v[7]=f2bf(f1.w);
        wfrag[g][s] = v;
      }
    }
  }

  const int ub = tid >> 4, j2 = (tid & 15) * 2;
  const int uA = u0 + j2;
  float creg0 = 0.f, creg1 = 0.f;
  if (tid < 128) {
    creg0 = c0[ub * 768 + uA];
    creg1 = c0[ub * 768 + uA + 1];
  }

  u16* hg = hglob + l * 24576;
  unsigned int* tg = tags + l * 64;
  const int swA = uA ^ ((ub & 7) << 3);

  if (tid < 128) {
    float v0 = h0[ub * 768 + uA], v1 = h0[ub * 768 + uA + 1];
    u16 h0a = f2bf(v0), h0b = f2bf(v1);
    u16 l0a = f2bf(v0 - bf2f(h0a)), l0b = f2bf(v1 - bf2f(h0b));
    a_st32((unsigned int*)&hg[ub * 768 + swA],
           (unsigned int)h0a | ((unsigned int)h0b << 16));
    a_st32((unsigned int*)&hg[(ub + 8) * 768 + swA],
           (unsigned int)l0a | ((unsigned int)l0b << 16));
  }
  __syncthreads();
  if (tid == 0) a_st32(&tg[grp], 1u);

  const int trow = l ? 257 : 256;
  const float* xrb = (l ? xW_w : xW_e) + ((long)ub * trow) * 3072 + uA;
  u16* outp = (l ? out_w : out_e) + (long)ub * 256 * 768 + uA;
  float2 xq0, xq1, xq2, xq3;
  if (tid < 128) {
    xq0 = *(const float2*)&xrb[0];
    xq1 = *(const float2*)&xrb[768];
    xq2 = *(const float2*)&xrb[1536];
    xq3 = *(const float2*)&xrb[2304];
  }

  for (int t = 0; t < 256; t++) {
    float2 nx0, nx1, nx2, nx3;
    if (tid < 128) {
      const float* xn = xrb + (long)(t + 1) * 3072;
      nx0 = *(const float2*)&xn[0];
      nx1 = *(const float2*)&xn[768];
      nx2 = *(const float2*)&xn[1536];
      nx3 = *(const float2*)&xn[2304];
    }

    {
      const unsigned int tgt = (unsigned int)(t + 1);
      const unsigned int* tp = tg + (t & 1) * 32;
      const bool need = (lane < 24) && (lane != grp);
      while (true) {
        unsigned int v = need ? a_ld32(&tp[lane]) : tgt;
        if (!__any(v < tgt)) break;
        __builtin_amdgcn_s_sleep(1);
      }
      asm volatile("" ::: "memory");
    }

    {
      const u64* hs8 = (const u64*)(hg + (t & 1) * 12288);
#pragma unroll
      for (int i = 0; i < 6; i++) {
        const int idx = i * 256 + tid;
        u64 a = a_ld64(&hs8[idx * 2 + 0]);
        u64 b = a_ld64(&hs8[idx * 2 + 1]);
        u64x2 vv; vv[0] = a; vv[1] = b;
        *(u64x2*)&ldsh[idx * 8] = vv;
      }
    }
    __syncthreads();                             // bar1

    f32x4 acc0 = {}, acc1 = {};
#pragma unroll
    for (int s = 0; s < 24; s++) {
      const int off = (c16 * 768 + s * 32 + half * 8) ^ ((c16 & 7) << 3);
      s16x8 a = *(const s16x8*)&ldsh[off];
      acc0 = __builtin_amdgcn_mfma_f32_16x16x32_bf16(a, wfrag[0][s], acc0, 0, 0, 0);
      acc1 = __builtin_amdgcn_mfma_f32_16x16x32_bf16(a, wfrag[1][s], acc1, 0, 0, 0);
    }
#pragma unroll
    for (int r = 0; r < 4; r++) {
      Gbuf[half * 4 + r][g0 + 0][uh][c16] = acc0[r];
      Gbuf[half * 4 + r][g0 + 1][uh][c16] = acc1[r];
    }
    __syncthreads();                             // bar2

    unsigned int hip = 0;
    float h20 = 0.f, h21 = 0.f, c20 = 0.f, c21 = 0.f;
    if (tid < 128) {
      const int uh0 = j2 >> 4, uc0 = j2 & 15;
      const int uc1 = (j2 + 1) & 15;
      float gi0 = Gbuf[ub][0][uh0][uc0] + Gbuf[ub + 8][0][uh0][uc0] + xq0.x;
      float gf0 = Gbuf[ub][1][uh0][uc0] + Gbuf[ub + 8][1][uh0][uc0] + xq1.x;
      float gg0 = Gbuf[ub][2][uh0][uc0] + Gbuf[ub + 8][2][uh0][uc0] + xq2.x;
      float go0 = Gbuf[ub][3][uh0][uc0] + Gbuf[ub + 8][3][uh0][uc0] + xq3.x;
      float gi1 = Gbuf[ub][0][uh0][uc1] + Gbuf[ub + 8][0][uh0][uc1] + xq0.y;
      float gf1 = Gbuf[ub][1][uh0][uc1] + Gbuf[ub + 8][1][uh0][uc1] + xq1.y;
      float gg1 = Gbuf[ub][2][uh0][uc1] + Gbuf[ub + 8][2][uh0][uc1] + xq2.y;
      float go1 = Gbuf[ub][3][uh0][uc1] + Gbuf[ub + 8][3][uh0][uc1] + xq3.y;
      float si0 = 1.f / (1.f + expf(-gi0)), si1 = 1.f / (1.f + expf(-gi1));
      float sf0 = 1.f / (1.f + expf(-gf0)), sf1 = 1.f / (1.f + expf(-gf1));
      float so0 = 1.f / (1.f + expf(-go0)), so1 = 1.f / (1.f + expf(-go1));
      c20 = sf0 * creg0 + si0 * tanhf(gg0);
      c21 = sf1 * creg1 + si1 * tanhf(gg1);
      h20 = so0 * tanhf(c20);
      h21 = so1 * tanhf(c21);
      creg0 = c20; creg1 = c21;
      u16 hiA = f2bf(h20), hiB = f2bf(h21);
      u16 loA = f2bf(h20 - bf2f(hiA)), loB = f2bf(h21 - bf2f(hiB));
      hip = (unsigned int)hiA | ((unsigned int)hiB << 16);
      unsigned int lop = (unsigned int)loA | ((unsigned int)loB << 16);
      u16* hb = hg + ((t + 1) & 1) * 12288;
      a_st32((unsigned int*)&hb[ub * 768 + swA], hip);
      a_st32((unsigned int*)&hb[(ub + 8) * 768 + swA], lop);
      xq0 = nx0; xq1 = nx1; xq2 = nx2; xq3 = nx3;
    }
    __syncthreads();               // bar3: drains vmcnt -> slices at L3
    if (tid == 0)
      a_st32(&tg[((t + 1) & 1) * 32 + grp], (unsigned int)(t + 2));

    if (tid < 128) {
      *(unsigned int*)&outp[(long)t * 768] = hip;
      if (l == 0 && t == 255) {
        *(float2*)&out_tail[43101120 + ub * 768 + uA] = make_float2(h20, h21);
        *(float2*)&out_tail[43107264 + ub * 768 + uA] = make_float2(c20, c21);
      }
    }
  }
}

// softmax over s (257 valid of 288) per (b,t) row; writes bf16 attn, zero pad
__global__ __launch_bounds__(256) void softmax_k(
    const float* __restrict__ scores, u16* __restrict__ attn)
{
  const int row = blockIdx.x;                 // 0..2047
  const float* src = scores + (long)row * 288;
  u16* dst = attn + (long)row * 288;
  const int tid = threadIdx.x;
  float v0 = (tid < 257) ? src[tid] : -1e30f;
  float v1 = (tid + 256 < 257) ? src[tid + 256] : -1e30f;
  float mx = fmaxf(v0, v1);
  for (int o = 32; o; o >>= 1) mx = fmaxf(mx, __shfl_xor(mx, o));
  __shared__ float sm[4];
  __shared__ float ss[4];
  if ((tid & 63) == 0) sm[tid >> 6] = mx;
  __syncthreads();
  mx = fmaxf(fmaxf(sm[0], sm[1]), fmaxf(sm[2], sm[3]));
  float e0 = (tid < 257) ? expf(v0 - mx) : 0.f;
  float e1 = (tid + 256 < 257) ? expf(v1 - mx) : 0.f;
  float s = e0 + e1;
  for (int o = 32; o; o >>= 1) s += __shfl_xor(s, o);
  if ((tid & 63) == 0) ss[tid >> 6] = s;
  __syncthreads();
  s = ss[0] + ss[1] + ss[2] + ss[3];
  float inv = 1.f / s;
  dst[tid] = f2bf(e0 * inv);
  if (tid + 256 < 288) dst[tid + 256] = f2bf(e1 * inv);
}

// log-softmax finalize: merge per-tile partials (166/row), then one
// subtract read+write pass (the full-row stats pass is fused into the GEMM).
__global__ __launch_bounds__(256) void logsoftmax_k(
    float* __restrict__ logits,
    const float* __restrict__ pmax, const float* __restrict__ psum)
{
  const int m = blockIdx.x;
  const int tid = threadIdx.x;
  float mm = -1e30f, ss = 0.f;
  if (tid < 166) {
    mm = pmax[(long)m * 166 + tid];
    ss = psum[(long)m * 166 + tid];
  }
#pragma unroll
  for (int off = 1; off < 64; off <<= 1) {
    float mo = __shfl_xor(mm, off), so = __shfl_xor(ss, off);
    float nm = fmaxf(mm, mo);
    ss = ss * expf(mm - nm) + so * expf(mo - nm);
    mm = nm;
  }
  __shared__ float wm[4], wsum[4];
  __shared__ float srs;
  if ((tid & 63) == 0) { wm[tid >> 6] = mm; wsum[tid >> 6] = ss; }
  __syncthreads();
  if (tid == 0) {
    float M = wm[0], S = wsum[0];
    for (int i = 1; i < 4; i++) {
      float nm = fmaxf(M, wm[i]);
      S = S * expf(M - nm) + wsum[i] * expf(wm[i] - nm);
      M = nm;
    }
    srs = M + logf(S);
  }
  __syncthreads();
  const float rs = srs;
  float* row = logits + (long)m * 21128;
  for (int i = tid * 4; i < 21128; i += 1024) {
    float4 v = *(const float4*)(row + i);
    v.x -= rs; v.y -= rs; v.z -= rs; v.w -= rs;
    *(float4*)(row + i) = v;
  }
}

// ---------------------------------------------------------------------------
extern "C" void kernel_launch(void* const* d_in, const int* in_sizes, int n_in,
                              void* d_out, int out_size, void* d_ws, size_t ws_size,
                              hipStream_t stream) {
  (void)in_sizes; (void)n_in; (void)out_size; (void)ws_size;
  const int*   input_edits = (const int*)d_in[0];
  const int*   org_ids     = (const int*)d_in[1];
  const int*   simp_sent   = (const int*)d_in[2];
  const float* h0      = (const float*)d_in[3];
  const float* c0      = (const float*)d_in[4];
  const float* encoder = (const float*)d_in[5];
  const float* emb     = (const float*)d_in[6];
  const float* Wih_e   = (const float*)d_in[7];
  const float* Whh_e   = (const float*)d_in[8];
  const float* b_e     = (const float*)d_in[9];
  const float* Wih_w   = (const float*)d_in[10];
  const float* Whh_w   = (const float*)d_in[11];
  const float* b_w     = (const float*)d_in[12];
  const float* W_attn  = (const float*)d_in[13];
  const float* W_align = (const float*)d_in[14];
  const float* W_mlp   = (const float*)d_in[15];
  const float* b_mlp   = (const float*)d_in[16];
  const float* W_out   = (const float*)d_in[17];
  const float* b_out   = (const float*)d_in[18];

  float* out = (float*)d_out;
  // --- d_out region doubles as scratch until the logits GEMM overwrites it
  float* xW_e = out;                               // [2048][3072] f32
  float* xW_w = out + 2048L * 3072;                // [2056][3072] f32
  u16* encd_bf = (u16*)(out + 2048L * 3072 + 2056L * 3072);  // [2176][768]

  // --- ws scratch
  char* p = (char*)d_ws;
  auto alloc = [&](size_t bytes) -> char* {
    char* r = p; p += (bytes + 255) & ~(size_t)255; return r;
  };
  u16* Wout_bf   = (u16*)alloc(21248L * 768 * 2);
  u16* Wihe_bf   = (u16*)alloc(3072L * 768 * 2);
  u16* Wihw_bf   = (u16*)alloc(3072L * 768 * 2);   // adjacent to Wihe_bf!
  u16* Wmlp_bf   = (u16*)alloc(768L * 3072 * 2);
  u16* Walign_bf = (u16*)alloc(768L * 768 * 2);
  u16* Wattn_bf  = (u16*)alloc(768L * 768 * 2);
  u16* gath_bf   = (u16*)alloc(4224L * 768 * 2);      // [2048 e | 2176 w]
  u16* enc_bf    = (u16*)alloc(8L * 384 * 768 * 2);   // padded batch stride
  u16* encT_bf   = (u16*)alloc(8L * 768 * 288 * 2);   // K padded to 288
  u16* oute_bf   = (u16*)alloc(2048L * 768 * 2);
  u16* outw_bf   = (u16*)alloc(2048L * 768 * 2);
  u16* key_bf    = (u16*)alloc(2048L * 768 * 2);
  u16* attn_bf   = (u16*)alloc(8L * 256 * 288 * 2);
  u16* ctx_bf    = (u16*)alloc(2048L * 768 * 2);
  u16* mlp_bf    = (u16*)alloc(2048L * 768 * 2);
  float* scores  = (float*)alloc(8L * 256 * 288 * 4);
  u16* hglob     = (u16*)alloc(2L * 2 * 12288 * 2);   // [l][buf][16][768]
  unsigned int* tags = (unsigned int*)alloc(256 * 4); // [l][buf][32]
  int* ki_bt     = (int*)alloc(2048 * 4);
  int* an_bt     = (int*)alloc(2048 * 4);
  float* pmax    = (float*)alloc(2040L * 166 * 4);
  float* psum    = (float*)alloc(2040L * 166 * 4);

  dim3 blk(256);
  const int BIGR = 1 << 30;

  // --- pre-LSTM casts + gathered-emb cast + counters + tag zero
  cast_pre<<<13313, blk, 0, stream>>>(emb, Wih_e, Wihe_bf, Wih_w, Wihw_bf,
                                      W_align, Walign_bf, encoder, encd_bf,
                                      gath_bf, input_edits, simp_sent,
                                      org_ids, ki_bt, an_bt, tags);

  // --- enc = tanh(encoder @ W_align^T) -> bf16, padded [8][384][768] layout
  gemm_bt<1, 0, 1, 0, 0, 0><<<dim3(6, 17, 1), blk, 0, stream>>>(
      encd_bf, Walign_bf, nullptr, enc_bf, nullptr,
      2056, 768, 768, 768, 768, 768, 0, 0, 0, 257, 294912L,
      nullptr, nullptr, 0, nullptr, nullptr);

  // --- both hoisted LSTM input projections in ONE z=2 dispatch (compact A)
  gemm_bt<0, 0, 0, 1, 0, 0><<<dim3(24, 17, 2), blk, 0, stream>>>(
      gath_bf, Wihe_bf, b_e, xW_e, nullptr,
      2048, 3072, 768, 768, 768, 3072, 1572864L, 2359296L, 6291456L, BIGR, 0,
      nullptr, b_w, 8, nullptr, nullptr);

  // --- recurrences (WGs 0-47) + shadow casts/transpose (WGs 48-255)
  lstm_persist<<<256, blk, 0, stream>>>(
      Whh_e, Whh_w, xW_e, xW_w, h0, c0, hglob, tags,
      oute_bf, outw_bf, out,
      W_out, Wout_bf, W_mlp, Wmlp_bf, W_attn, Wattn_bf, enc_bf, encT_bf);

  // --- attention (proven 3-kernel chain)
  gemm_bt<1, 0, 0, 0, 0, 0><<<dim3(6, 16, 1), blk, 0, stream>>>(
      oute_bf, Wattn_bf, nullptr, key_bf, nullptr,
      2048, 768, 768, 768, 768, 768, 0, 0, 0, BIGR, 0,
      nullptr, nullptr, 0, nullptr, nullptr);
  gemm_bt<0, 0, 0, 0, 0, 0><<<dim3(3, 2, 8), blk, 0, stream>>>(
      key_bf, enc_bf, nullptr, scores, nullptr,
      256, 257, 768, 768, 768, 288, 196608L, 294912L, 73728L, BIGR, 0,
      nullptr, nullptr, 0, nullptr, nullptr);
  softmax_k<<<2048, blk, 0, stream>>>(scores, attn_bf);
  gemm_bt<1, 0, 0, 0, 0, 0><<<dim3(6, 2, 8), blk, 0, stream>>>(
      attn_bf, encT_bf, nullptr, ctx_bf, nullptr,
      256, 768, 288, 288, 288, 768, 73728L, 221184L, 196608L, BIGR, 0,
      nullptr, nullptr, 0, nullptr, nullptr);

  // --- MLP GEMM with fused feature gather
  gemm_mlp<<<dim3(6, 16), blk, 0, stream>>>(
      oute_bf, ctx_bf, enc_bf, outw_bf, ki_bt, an_bt,
      Wmlp_bf, b_mlp, mlp_bf);

  // --- out GEMM: SWAPXY for Wout L2 reuse + fused per-tile softmax partials
  gemm_bt<0, 0, 0, 1, 1, 1><<<dim3(16, 166, 1), blk, 0, stream>>>(
      mlp_bf, Wout_bf, b_out, out, nullptr,
      2040, 21128, 768, 768, 768, 21128, 0, 0, 0, BIGR, 0,
      nullptr, nullptr, 0, pmax, psum);

  // --- log_softmax finalize: merge partials + single subtract pass
  logsoftmax_k<<<2040, blk, 0, stream>>>(out, pmax, psum);
}

// Round 14
// 1638.750 us; speedup vs baseline: 1.0458x; 1.0458x over previous
//
#include <hip/hip_runtime.h>
#include <hip/hip_bf16.h>

typedef short s16x8 __attribute__((ext_vector_type(8)));
typedef float f32x4 __attribute__((ext_vector_type(4)));
typedef unsigned short u16;
typedef unsigned short u16x4 __attribute__((ext_vector_type(4)));
typedef unsigned long long u64;
typedef unsigned long long u64x2 __attribute__((ext_vector_type(2)));

__device__ __forceinline__ u16 f2bf(float f) {
  __hip_bfloat16 h = __float2bfloat16(f);
  u16 u;
  __builtin_memcpy(&u, &h, sizeof(u));
  return u;
}
__device__ __forceinline__ float bf2f(u16 u) {
  unsigned int x = ((unsigned int)u) << 16;
  float f;
  __builtin_memcpy(&f, &x, 4);
  return f;
}

// device-scope relaxed atomics (serviced at L3 coherence point; no fences)
__device__ __forceinline__ unsigned int a_ld32(const unsigned int* p) {
  return __hip_atomic_load(p, __ATOMIC_RELAXED, __HIP_MEMORY_SCOPE_AGENT);
}
__device__ __forceinline__ u64 a_ld64(const u64* p) {
  return __hip_atomic_load(p, __ATOMIC_RELAXED, __HIP_MEMORY_SCOPE_AGENT);
}
__device__ __forceinline__ void a_st32(unsigned int* p, unsigned int v) {
  __hip_atomic_store(p, v, __ATOMIC_RELAXED, __HIP_MEMORY_SCOPE_AGENT);
}

// async global->LDS, 16B per lane; lds addr must be wave-uniform base
__device__ __forceinline__ void gload16(const void* g, void* l) {
  __builtin_amdgcn_global_load_lds(
      (const __attribute__((address_space(1))) unsigned int*)g,
      (__attribute__((address_space(3))) unsigned int*)l, 16, 0, 0);
}

// ---------------------------------------------------------------------------
// Generic bf16 MFMA GEMM:  C[m,n] = act( sum_k A[m,k]*B[n,k] + bias[n] )
// 128x128 tile, BK=32, 256 threads. Staging via global_load_lds width-16.
// z-batched; optional per-z overrides (ids2/bias2/dM). SWAPXY: M-tiles on
// blockIdx.x (fast axis) for B-slab L2 reuse on wide-N GEMMs.
// ---------------------------------------------------------------------------
template<int CBF16, int GATHER, int TANHA, int BIAS, int SWAPXY>
__global__ __launch_bounds__(256) void gemm_bt(
    const u16* __restrict__ A, const u16* __restrict__ B,
    const float* __restrict__ bias, void* __restrict__ Cv,
    const int* __restrict__ ids,
    int M, int N, int K, int lda, int ldb, int ldc,
    long sAz, long sBz, long sCz, int rpb, long cbs,
    const int* __restrict__ ids2, const float* __restrict__ bias2, int dM)
{
  __shared__ u16 sA[4096];
  __shared__ u16 sB[4096];
  const int tid = threadIdx.x;
  const int z = blockIdx.z;
  if (z) {
    if (dM) M += dM;
    if (ids2) ids = ids2;
    if (bias2) bias = bias2;
  }
  const int m0 = (SWAPXY ? blockIdx.x : blockIdx.y) * 128;
  const int n0 = (SWAPXY ? blockIdx.y : blockIdx.x) * 128;
  const u16* Ab = A + z * sAz;
  const u16* Bb = B + z * sBz;
  const int w = tid >> 6, lane = tid & 63;
  const int wr = w >> 1, wc = w & 1;
  const int lr = lane & 15, lk = lane >> 4;
  f32x4 acc[4][4] = {};
  const int e0 = tid * 8, e1 = e0 + 2048;
  const int r0 = e0 >> 5, c0 = e0 & 31;
  const int r1 = e1 >> 5, c1 = e1 & 31;
  long arow0, arow1;
  if (GATHER) {
    int i0 = m0 + r0; if (i0 >= M) i0 = M - 1;
    int i1 = m0 + r1; if (i1 >= M) i1 = M - 1;
    arow0 = (long)ids[i0] * lda;
    arow1 = (long)ids[i1] * lda;
  } else {
    arow0 = (long)(m0 + r0) * lda;
    arow1 = (long)(m0 + r1) * lda;
  }
  const long brow0 = (long)(n0 + r0) * ldb;
  const long brow1 = (long)(n0 + r1) * ldb;
  char* sAc = (char*)sA;
  char* sBc = (char*)sB;
  const size_t cb = (size_t)w * 1024;
  for (int kt = 0; kt < K; kt += 32) {
    __syncthreads();
    gload16(Ab + arow0 + kt + c0, sAc + cb);
    gload16(Ab + arow1 + kt + c1, sAc + 4096 + cb);
    gload16(Bb + brow0 + kt + c0, sBc + cb);
    gload16(Bb + brow1 + kt + c1, sBc + 4096 + cb);
    __syncthreads();
    s16x8 af[4], bf[4];
#pragma unroll
    for (int i = 0; i < 4; i++) {
      af[i] = *(const s16x8*)&sA[(wr*64 + i*16 + lr)*32 + lk*8];
      bf[i] = *(const s16x8*)&sB[(wc*64 + i*16 + lr)*32 + lk*8];
    }
#pragma unroll
    for (int mi = 0; mi < 4; mi++)
#pragma unroll
      for (int ni = 0; ni < 4; ni++)
        acc[mi][ni] = __builtin_amdgcn_mfma_f32_16x16x32_bf16(af[mi], bf[ni], acc[mi][ni], 0, 0, 0);
  }
#pragma unroll
  for (int mi = 0; mi < 4; mi++) {
#pragma unroll
    for (int ni = 0; ni < 4; ni++) {
#pragma unroll
      for (int r = 0; r < 4; r++) {
        int gm = m0 + wr*64 + mi*16 + lk*4 + r;
        int gn = n0 + wc*64 + ni*16 + lr;
        if (gm < M && gn < N) {
          float v = acc[mi][ni][r];
          if (BIAS) v += bias[gn];
          if (TANHA) v = tanhf(v);
          long ci = z * sCz + (long)(gm / rpb) * cbs + (long)(gm % rpb) * ldc + gn;
          if (CBF16) ((u16*)Cv)[ci] = f2bf(v);
          else       ((float*)Cv)[ci] = v;
        }
      }
    }
  }
}

// ---------------------------------------------------------------------------
// MLP GEMM with fused feature-concat A-gather. A row m (of 2040) is the
// virtual concat [oute | ctx | enc(an) | outw] (4 x 768 cols). Each BK=32
// K-slab lies entirely within one segment -> one pointer select per iter.
// C = tanh(A @ Wmlp^T + b_mlp) as bf16 [2048][768] (rows >=2040 masked).
// ---------------------------------------------------------------------------
__global__ __launch_bounds__(256) void gemm_mlp(
    const u16* __restrict__ oute, const u16* __restrict__ ctxp,
    const u16* __restrict__ encp, const u16* __restrict__ outw,
    const int* __restrict__ ki_bt, const int* __restrict__ an_bt,
    const u16* __restrict__ B, const float* __restrict__ bias,
    u16* __restrict__ C)
{
  __shared__ u16 sA[4096];
  __shared__ u16 sB[4096];
  const int tid = threadIdx.x;
  const int m0 = blockIdx.y * 128, n0 = blockIdx.x * 128;
  const int w = tid >> 6, lane = tid & 63;
  const int wr = w >> 1, wc = w & 1;
  const int lr = lane & 15, lk = lane >> 4;
  f32x4 acc[4][4] = {};
  const int e0 = tid * 8, e1 = e0 + 2048;
  const int r0 = e0 >> 5, c0 = e0 & 31;
  const int r1 = e1 >> 5, c1 = e1 & 31;
  const u16 *b00, *b01, *b02, *b03, *b10, *b11, *b12, *b13;
  {
    int m = m0 + r0; if (m >= 2040) m = 2039;
    int b = m / 255, t = m - b * 255;
    b00 = oute + ((long)(b * 256 + t)) * 768;
    b01 = ctxp + ((long)(b * 256 + t)) * 768;
    b02 = encp + ((long)(b * 384 + an_bt[m])) * 768;
    b03 = outw + ((long)(b * 256 + ki_bt[m])) * 768;
    m = m0 + r1; if (m >= 2040) m = 2039;
    b = m / 255; t = m - b * 255;
    b10 = oute + ((long)(b * 256 + t)) * 768;
    b11 = ctxp + ((long)(b * 256 + t)) * 768;
    b12 = encp + ((long)(b * 384 + an_bt[m])) * 768;
    b13 = outw + ((long)(b * 256 + ki_bt[m])) * 768;
  }
  const long brow0 = (long)(n0 + r0) * 3072;
  const long brow1 = (long)(n0 + r1) * 3072;
  char* sAc = (char*)sA;
  char* sBc = (char*)sB;
  const size_t cb = (size_t)w * 1024;
  for (int kt = 0; kt < 3072; kt += 32) {
    const int seg = kt / 768, off = kt - seg * 768;
    const u16* a0 = (seg == 0 ? b00 : seg == 1 ? b01 : seg == 2 ? b02 : b03) + off + c0;
    const u16* a1 = (seg == 0 ? b10 : seg == 1 ? b11 : seg == 2 ? b12 : b13) + off + c1;
    __syncthreads();
    gload16(a0, sAc + cb);
    gload16(a1, sAc + 4096 + cb);
    gload16(B + brow0 + kt + c0, sBc + cb);
    gload16(B + brow1 + kt + c1, sBc + 4096 + cb);
    __syncthreads();
    s16x8 af[4], bf[4];
#pragma unroll
    for (int i = 0; i < 4; i++) {
      af[i] = *(const s16x8*)&sA[(wr*64 + i*16 + lr)*32 + lk*8];
      bf[i] = *(const s16x8*)&sB[(wc*64 + i*16 + lr)*32 + lk*8];
    }
#pragma unroll
    for (int mi = 0; mi < 4; mi++)
#pragma unroll
      for (int ni = 0; ni < 4; ni++)
        acc[mi][ni] = __builtin_amdgcn_mfma_f32_16x16x32_bf16(af[mi], bf[ni], acc[mi][ni], 0, 0, 0);
  }
#pragma unroll
  for (int mi = 0; mi < 4; mi++) {
#pragma unroll
    for (int ni = 0; ni < 4; ni++) {
#pragma unroll
      for (int r = 0; r < 4; r++) {
        int gm = m0 + wr*64 + mi*16 + lk*4 + r;
        int gn = n0 + wc*64 + ni*16 + lr;
        if (gm < 2040 && gn < 768) {
          float v = tanhf(acc[mi][ni][r] + bias[gn]);
          C[(long)gm * 768 + gn] = f2bf(v);
        }
      }
    }
  }
}

// ---------------------------------------------------------------------------
// Pre-LSTM casts + gathered-emb cast + counter recurrence + tag zeroing.
// ---------------------------------------------------------------------------
__global__ __launch_bounds__(256) void cast_pre(
    const float* __restrict__ emb,
    const float* __restrict__ Wihe, u16* __restrict__ Wihe_bf,
    const float* __restrict__ Wihw, u16* __restrict__ Wihw_bf,
    const float* __restrict__ Walign, u16* __restrict__ Walign_bf,
    const float* __restrict__ encoder, u16* __restrict__ encd_bf,
    u16* __restrict__ gath_bf,
    const int* __restrict__ input_edits, const int* __restrict__ simp_sent,
    const int* __restrict__ org_ids,
    int* __restrict__ ki_bt, int* __restrict__ an_bt,
    unsigned int* __restrict__ tags)
{
  int r = blockIdx.x;
  if (r == 13312) {
    int b = threadIdx.x;
    tags[b] = 0;
    if (b >= 8) return;
    int kd = 0, ki = 0, an = 0;
    for (int t = 0; t < 255; t++) {
      int a = input_edits[b * 256 + t + 1];
      ki_bt[b * 255 + t] = ki;
      an_bt[b * 255 + t] = an;
      int kd2 = kd + ((a == 1) || (a == 2) ? 1 : 0);
      int ns = (a != 2) && (a != 102) && (a != 0);
      int ki2 = ki + (ns ? 1 : 0);
      int is_ins = ns && (a != 1);
      int nia = (org_ids[b * 257 + an + 1] == 103);
      int mx = (kd2 > an) ? kd2 : an;
      int an2 = (is_ins && nia) ? (an + 1) : mx;
      kd = kd2; ki = ki2; an = an2;
    }
    return;
  }
  const float* src; u16* dst; int valid, cols;
  if (r < 3072)                   { src=Wihe + (long)r*768;   dst=Wihe_bf + (long)r*768;   valid=1; cols=768; }
  else if ((r -= 3072) < 3072)    { src=Wihw + (long)r*768;   dst=Wihw_bf + (long)r*768;   valid=1; cols=768; }
  else if ((r -= 3072) < 768)     { src=Walign + (long)r*768; dst=Walign_bf + (long)r*768; valid=1; cols=768; }
  else if ((r -= 768) < 2176)     { src=encoder + (long)r*768; dst=encd_bf + (long)r*768;  valid=(r<2056); cols=768; }
  else if ((r -= 2176) < 2048)    { src=emb + (long)input_edits[r]*768; dst=gath_bf + (long)r*768; valid=1; cols=768; }
  else { r -= 2048;                 int ok=(r<2056);
                                    src=emb + (ok ? (long)simp_sent[r]*768 : 0); 
                                    dst=gath_bf + (long)(2048+r)*768; valid=ok; cols=768; }
  for (int c = threadIdx.x; c < cols; c += 256) {
    float v = valid ? src[c] : 0.f;
    dst[c] = f2bf(v);
  }
}

// ---------------------------------------------------------------------------
// Persistent LSTM (R6/R9 proven structure) + SHADOW WGs (R10).
// ---------------------------------------------------------------------------
__global__ __launch_bounds__(256, 1) void lstm_persist(
    const float* __restrict__ Whh_e, const float* __restrict__ Whh_w,
    const float* __restrict__ xW_e, const float* __restrict__ xW_w,
    const float* __restrict__ h0, const float* __restrict__ c0,
    u16* __restrict__ hglob, unsigned int* __restrict__ tags,
    u16* __restrict__ out_e, u16* __restrict__ out_w,
    float* __restrict__ out_tail,
    const float* __restrict__ Wout, u16* __restrict__ Wout_bf,
    const float* __restrict__ Wmlp, u16* __restrict__ Wmlp_bf,
    const float* __restrict__ Wattn, u16* __restrict__ Wattn_bf,
    const u16* __restrict__ enc_bf, u16* __restrict__ encT_bf)
{
  const int wg = blockIdx.x;
  const int tid = threadIdx.x;

  __shared__ u16 ldsh[12288];
  __shared__ float Gbuf[16][4][2][16];

  if (wg >= 48) {
    // ================= SHADOW PATH =================
    const int swg = wg - 48;
    u16 (*tile)[33] = (u16(*)[33])ldsh;
    const int TOT = 21248 + 768 + 768 + 1728;
    for (int u = swg; u < TOT; u += 208) {
      if (u < 21248) {
        const float* src = Wout + (long)u * 768;
        u16* dst = Wout_bf + (long)u * 768;
        bool ok = (u < 21128);
        for (int c = tid; c < 768; c += 256)
          dst[c] = f2bf(ok ? src[c] : 0.f);
      } else if (u < 22016) {
        int r = u - 21248;
        const float* src = Wmlp + (long)r * 3072;
        u16* dst = Wmlp_bf + (long)r * 3072;
        for (int c = tid; c < 3072; c += 256)
          dst[c] = f2bf(src[c]);
      } else if (u < 22784) {
        int r = u - 22016;
        const float* src = Wattn + (long)r * 768;
        u16* dst = Wattn_bf + (long)r * 768;
        for (int c = tid; c < 768; c += 256)
          dst[c] = f2bf(src[c]);
      } else {
        int tau = u - 22784;
        int s0 = (tau % 9) * 32;
        int rem = tau / 9;
        int hh0 = (rem % 24) * 32;
        int b = rem / 24;
        const int tx = tid & 31, ty = tid >> 5;
#pragma unroll
        for (int i = 0; i < 32; i += 8) {
          int s = s0 + ty + i;
          u16 v = (s < 257) ? enc_bf[((long)b * 384 + s) * 768 + hh0 + tx] : (u16)0;
          tile[ty + i][tx] = v;
        }
        __syncthreads();
#pragma unroll
        for (int i = 0; i < 32; i += 8) {
          int h = hh0 + ty + i;
          encT_bf[((long)b * 768 + h) * 288 + s0 + tx] = tile[tx][ty + i];
        }
        __syncthreads();
      }
    }
    return;
  }

  // ================= SYNC PATH (exact R9) =================
  const int l = wg / 24, grp = wg % 24;
  const int u0 = grp * 32;
  const int w = tid >> 6, lane = tid & 63;
  const int c16 = lane & 15, half = lane >> 4;
  const int uh = w >> 1, g0 = (w & 1) * 2;

  s16x8 wfrag[2][24];
  {
    const float* Wbase = l ? Whh_w : Whh_e;
#pragma unroll
    for (int g = 0; g < 2; g++) {
      const float* Wsrc = Wbase + (long)((g0 + g) * 768 + u0 + uh * 16 + c16) * 768 + half * 8;
#pragma unroll
      for (int s = 0; s < 24; s++) {
        float4 f0 = *(const float4*)(Wsrc + s * 32);
        float4 f1 = *(const float4*)(Wsrc + s * 32 + 4);
        s16x8 v;
        v[0]=f2bf(f0.x); v[1]=f2bf(f0.y); v[2]=f2bf(f0.z); v[3]=f2bf(f0.w);
        v[4]=f2bf(f1.x); v[5]=f2bf(f1.y); v[6]=f2bf(f1.z); v[7]=f2bf(f1.w);
        wfrag[g][s] = v;
      }
    }
  }

  const int ub = tid >> 4, j2 = (tid & 15) * 2;
  const int uA = u0 + j2;
  float creg0 = 0.f, creg1 = 0.f;
  if (tid < 128) {
    creg0 = c0[ub * 768 + uA];
    creg1 = c0[ub * 768 + uA + 1];
  }

  u16* hg = hglob + l * 24576;
  unsigned int* tg = tags + l * 64;
  const int swA = uA ^ ((ub & 7) << 3);

  if (tid < 128) {
    float v0 = h0[ub * 768 + uA], v1 = h0[ub * 768 + uA + 1];
    u16 h0a = f2bf(v0), h0b = f2bf(v1);
    u16 l0a = f2bf(v0 - bf2f(h0a)), l0b = f2bf(v1 - bf2f(h0b));
    a_st32((unsigned int*)&hg[ub * 768 + swA],
           (unsigned int)h0a | ((unsigned int)h0b << 16));
    a_st32((unsigned int*)&hg[(ub + 8) * 768 + swA],
           (unsigned int)l0a | ((unsigned int)l0b << 16));
  }
  __syncthreads();
  if (tid == 0) a_st32(&tg[grp], 1u);

  const int trow = l ? 257 : 256;
  const float* xrb = (l ? xW_w : xW_e) + ((long)ub * trow) * 3072 + uA;
  u16* outp = (l ? out_w : out_e) + (long)ub * 256 * 768 + uA;
  float2 xq0, xq1, xq2, xq3;
  if (tid < 128) {
    xq0 = *(const float2*)&xrb[0];
    xq1 = *(const float2*)&xrb[768];
    xq2 = *(const float2*)&xrb[1536];
    xq3 = *(const float2*)&xrb[2304];
  }

  for (int t = 0; t < 256; t++) {
    float2 nx0, nx1, nx2, nx3;
    if (tid < 128) {
      const float* xn = xrb + (long)(t + 1) * 3072;
      nx0 = *(const float2*)&xn[0];
      nx1 = *(const float2*)&xn[768];
      nx2 = *(const float2*)&xn[1536];
      nx3 = *(const float2*)&xn[2304];
    }

    {
      const unsigned int tgt = (unsigned int)(t + 1);
      const unsigned int* tp = tg + (t & 1) * 32;
      const bool need = (lane < 24) && (lane != grp);
      while (true) {
        unsigned int v = need ? a_ld32(&tp[lane]) : tgt;
        if (!__any(v < tgt)) break;
        __builtin_amdgcn_s_sleep(1);
      }
      asm volatile("" ::: "memory");
    }

    {
      const u64* hs8 = (const u64*)(hg + (t & 1) * 12288);
#pragma unroll
      for (int i = 0; i < 6; i++) {
        const int idx = i * 256 + tid;
        u64 a = a_ld64(&hs8[idx * 2 + 0]);
        u64 b = a_ld64(&hs8[idx * 2 + 1]);
        u64x2 vv; vv[0] = a; vv[1] = b;
        *(u64x2*)&ldsh[idx * 8] = vv;
      }
    }
    __syncthreads();                             // bar1

    f32x4 acc0 = {}, acc1 = {};
#pragma unroll
    for (int s = 0; s < 24; s++) {
      const int off = (c16 * 768 + s * 32 + half * 8) ^ ((c16 & 7) << 3);
      s16x8 a = *(const s16x8*)&ldsh[off];
      acc0 = __builtin_amdgcn_mfma_f32_16x16x32_bf16(a, wfrag[0][s], acc0, 0, 0, 0);
      acc1 = __builtin_amdgcn_mfma_f32_16x16x32_bf16(a, wfrag[1][s], acc1, 0, 0, 0);
    }
#pragma unroll
    for (int r = 0; r < 4; r++) {
      Gbuf[half * 4 + r][g0 + 0][uh][c16] = acc0[r];
      Gbuf[half * 4 + r][g0 + 1][uh][c16] = acc1[r];
    }
    __syncthreads();                             // bar2

    unsigned int hip = 0;
    float h20 = 0.f, h21 = 0.f, c20 = 0.f, c21 = 0.f;
    if (tid < 128) {
      const int uh0 = j2 >> 4, uc0 = j2 & 15;
      const int uc1 = (j2 + 1) & 15;
      float gi0 = Gbuf[ub][0][uh0][uc0] + Gbuf[ub + 8][0][uh0][uc0] + xq0.x;
      float gf0 = Gbuf[ub][1][uh0][uc0] + Gbuf[ub + 8][1][uh0][uc0] + xq1.x;
      float gg0 = Gbuf[ub][2][uh0][uc0] + Gbuf[ub + 8][2][uh0][uc0] + xq2.x;
      float go0 = Gbuf[ub][3][uh0][uc0] + Gbuf[ub + 8][3][uh0][uc0] + xq3.x;
      float gi1 = Gbuf[ub][0][uh0][uc1] + Gbuf[ub + 8][0][uh0][uc1] + xq0.y;
      float gf1 = Gbuf[ub][1][uh0][uc1] + Gbuf[ub + 8][1][uh0][uc1] + xq1.y;
      float gg1 = Gbuf[ub][2][uh0][uc1] + Gbuf[ub + 8][2][uh0][uc1] + xq2.y;
      float go1 = Gbuf[ub][3][uh0][uc1] + Gbuf[ub + 8][3][uh0][uc1] + xq3.y;
      float si0 = 1.f / (1.f + expf(-gi0)), si1 = 1.f / (1.f + expf(-gi1));
      float sf0 = 1.f / (1.f + expf(-gf0)), sf1 = 1.f / (1.f + expf(-gf1));
      float so0 = 1.f / (1.f + expf(-go0)), so1 = 1.f / (1.f + expf(-go1));
      c20 = sf0 * creg0 + si0 * tanhf(gg0);
      c21 = sf1 * creg1 + si1 * tanhf(gg1);
      h20 = so0 * tanhf(c20);
      h21 = so1 * tanhf(c21);
      creg0 = c20; creg1 = c21;
      u16 hiA = f2bf(h20), hiB = f2bf(h21);
      u16 loA = f2bf(h20 - bf2f(hiA)), loB = f2bf(h21 - bf2f(hiB));
      hip = (unsigned int)hiA | ((unsigned int)hiB << 16);
      unsigned int lop = (unsigned int)loA | ((unsigned int)loB << 16);
      u16* hb = hg + ((t + 1) & 1) * 12288;
      a_st32((unsigned int*)&hb[ub * 768 + swA], hip);
      a_st32((unsigned int*)&hb[(ub + 8) * 768 + swA], lop);
      xq0 = nx0; xq1 = nx1; xq2 = nx2; xq3 = nx3;
    }
    __syncthreads();               // bar3: drains vmcnt -> slices at L3
    if (tid == 0)
      a_st32(&tg[((t + 1) & 1) * 32 + grp], (unsigned int)(t + 2));

    if (tid < 128) {
      *(unsigned int*)&outp[(long)t * 768] = hip;
      if (l == 0 && t == 255) {
        *(float2*)&out_tail[43101120 + ub * 768 + uA] = make_float2(h20, h21);
        *(float2*)&out_tail[43107264 + ub * 768 + uA] = make_float2(c20, c21);
      }
    }
  }
}

// softmax over s (257 valid of 288) per (b,t) row; writes bf16 attn, zero pad
__global__ __launch_bounds__(256) void softmax_k(
    const float* __restrict__ scores, u16* __restrict__ attn)
{
  const int row = blockIdx.x;                 // 0..2047
  const float* src = scores + (long)row * 288;
  u16* dst = attn + (long)row * 288;
  const int tid = threadIdx.x;
  float v0 = (tid < 257) ? src[tid] : -1e30f;
  float v1 = (tid + 256 < 257) ? src[tid + 256] : -1e30f;
  float mx = fmaxf(v0, v1);
  for (int o = 32; o; o >>= 1) mx = fmaxf(mx, __shfl_xor(mx, o));
  __shared__ float sm[4];
  __shared__ float ss[4];
  if ((tid & 63) == 0) sm[tid >> 6] = mx;
  __syncthreads();
  mx = fmaxf(fmaxf(sm[0], sm[1]), fmaxf(sm[2], sm[3]));
  float e0 = (tid < 257) ? expf(v0 - mx) : 0.f;
  float e1 = (tid + 256 < 257) ? expf(v1 - mx) : 0.f;
  float s = e0 + e1;
  for (int o = 32; o; o >>= 1) s += __shfl_xor(s, o);
  if ((tid & 63) == 0) ss[tid >> 6] = s;
  __syncthreads();
  s = ss[0] + ss[1] + ss[2] + ss[3];
  float inv = 1.f / s;
  dst[tid] = f2bf(e0 * inv);
  if (tid + 256 < 288) dst[tid + 256] = f2bf(e1 * inv);
}

// fused log_softmax: per-row stat then in-place subtract (row stays in L2)
__global__ __launch_bounds__(256) void logsoftmax_k(float* __restrict__ logits)
{
  const int m = blockIdx.x;
  float* row = logits + (long)m * 21128;
  const int tid = threadIdx.x;
  float mx = -1e30f, sm = 0.f;
  for (int i = tid * 4; i < 21128; i += 1024) {
    float4 v = *(const float4*)(row + i);
    float m4 = fmaxf(fmaxf(v.x, v.y), fmaxf(v.z, v.w));
    if (m4 > mx) { sm *= expf(mx - m4); mx = m4; }
    sm += expf(v.x - mx) + expf(v.y - mx) + expf(v.z - mx) + expf(v.w - mx);
  }
  for (int o = 32; o; o >>= 1) {
    float mo = __shfl_xor(mx, o), so = __shfl_xor(sm, o);
    float nm = fmaxf(mx, mo);
    sm = sm * expf(mx - nm) + so * expf(mo - nm);
    mx = nm;
  }
  __shared__ float wm[4], wsum[4];
  __shared__ float srs;
  if ((tid & 63) == 0) { wm[tid >> 6] = mx; wsum[tid >> 6] = sm; }
  __syncthreads();
  if (tid == 0) {
    float M = wm[0], S = wsum[0];
    for (int i = 1; i < 4; i++) {
      float nm = fmaxf(M, wm[i]);
      S = S * expf(M - nm) + wsum[i] * expf(wm[i] - nm);
      M = nm;
    }
    srs = M + logf(S);
  }
  __syncthreads();
  const float rs = srs;
  for (int i = tid * 4; i < 21128; i += 1024) {
    float4 v = *(const float4*)(row + i);
    v.x -= rs; v.y -= rs; v.z -= rs; v.w -= rs;
    *(float4*)(row + i) = v;
  }
}

// ---------------------------------------------------------------------------
extern "C" void kernel_launch(void* const* d_in, const int* in_sizes, int n_in,
                              void* d_out, int out_size, void* d_ws, size_t ws_size,
                              hipStream_t stream) {
  (void)in_sizes; (void)n_in; (void)out_size; (void)ws_size;
  const int*   input_edits = (const int*)d_in[0];
  const int*   org_ids     = (const int*)d_in[1];
  const int*   simp_sent   = (const int*)d_in[2];
  const float* h0      = (const float*)d_in[3];
  const float* c0      = (const float*)d_in[4];
  const float* encoder = (const float*)d_in[5];
  const float* emb     = (const float*)d_in[6];
  const float* Wih_e   = (const float*)d_in[7];
  const float* Whh_e   = (const float*)d_in[8];
  const float* b_e     = (const float*)d_in[9];
  const float* Wih_w   = (const float*)d_in[10];
  const float* Whh_w   = (const float*)d_in[11];
  const float* b_w     = (const float*)d_in[12];
  const float* W_attn  = (const float*)d_in[13];
  const float* W_align = (const float*)d_in[14];
  const float* W_mlp   = (const float*)d_in[15];
  const float* b_mlp   = (const float*)d_in[16];
  const float* W_out   = (const float*)d_in[17];
  const float* b_out   = (const float*)d_in[18];

  float* out = (float*)d_out;
  // --- d_out region doubles as scratch until the logits GEMM overwrites it
  float* xW_e = out;                               // [2048][3072] f32
  float* xW_w = out + 2048L * 3072;                // [2056][3072] f32
  u16* encd_bf = (u16*)(out + 2048L * 3072 + 2056L * 3072);  // [2176][768]

  // --- ws scratch
  char* p = (char*)d_ws;
  auto alloc = [&](size_t bytes) -> char* {
    char* r = p; p += (bytes + 255) & ~(size_t)255; return r;
  };
  u16* Wout_bf   = (u16*)alloc(21248L * 768 * 2);
  u16* Wihe_bf   = (u16*)alloc(3072L * 768 * 2);
  u16* Wihw_bf   = (u16*)alloc(3072L * 768 * 2);   // adjacent to Wihe_bf!
  u16* Wmlp_bf   = (u16*)alloc(768L * 3072 * 2);
  u16* Walign_bf = (u16*)alloc(768L * 768 * 2);
  u16* Wattn_bf  = (u16*)alloc(768L * 768 * 2);
  u16* gath_bf   = (u16*)alloc(4224L * 768 * 2);      // [2048 e | 2176 w]
  u16* enc_bf    = (u16*)alloc(8L * 384 * 768 * 2);   // padded batch stride
  u16* encT_bf   = (u16*)alloc(8L * 768 * 288 * 2);   // K padded to 288
  u16* oute_bf   = (u16*)alloc(2048L * 768 * 2);
  u16* outw_bf   = (u16*)alloc(2048L * 768 * 2);
  u16* key_bf    = (u16*)alloc(2048L * 768 * 2);
  u16* attn_bf   = (u16*)alloc(8L * 256 * 288 * 2);
  u16* ctx_bf    = (u16*)alloc(2048L * 768 * 2);
  u16* mlp_bf    = (u16*)alloc(2048L * 768 * 2);
  float* scores  = (float*)alloc(8L * 256 * 288 * 4);
  u16* hglob     = (u16*)alloc(2L * 2 * 12288 * 2);   // [l][buf][16][768]
  unsigned int* tags = (unsigned int*)alloc(256 * 4); // [l][buf][32]
  int* ki_bt     = (int*)alloc(2048 * 4);
  int* an_bt     = (int*)alloc(2048 * 4);

  dim3 blk(256);
  const int BIGR = 1 << 30;

  // --- pre-LSTM casts + gathered-emb cast + counters + tag zero
  cast_pre<<<13313, blk, 0, stream>>>(emb, Wih_e, Wihe_bf, Wih_w, Wihw_bf,
                                      W_align, Walign_bf, encoder, encd_bf,
                                      gath_bf, input_edits, simp_sent,
                                      org_ids, ki_bt, an_bt, tags);

  // --- enc = tanh(encoder @ W_align^T) -> bf16, padded [8][384][768] layout
  gemm_bt<1, 0, 1, 0, 0><<<dim3(6, 17, 1), blk, 0, stream>>>(
      encd_bf, Walign_bf, nullptr, enc_bf, nullptr,
      2056, 768, 768, 768, 768, 768, 0, 0, 0, 257, 294912L,
      nullptr, nullptr, 0);

  // --- both hoisted LSTM input projections in ONE z=2 dispatch (compact A)
  gemm_bt<0, 0, 0, 1, 0><<<dim3(24, 17, 2), blk, 0, stream>>>(
      gath_bf, Wihe_bf, b_e, xW_e, nullptr,
      2048, 3072, 768, 768, 768, 3072, 1572864L, 2359296L, 6291456L, BIGR, 0,
      nullptr, b_w, 8);

  // --- recurrences (WGs 0-47) + shadow casts/transpose (WGs 48-255)
  lstm_persist<<<256, blk, 0, stream>>>(
      Whh_e, Whh_w, xW_e, xW_w, h0, c0, hglob, tags,
      oute_bf, outw_bf, out,
      W_out, Wout_bf, W_mlp, Wmlp_bf, W_attn, Wattn_bf, enc_bf, encT_bf);

  // --- attention (R10 proven 3-kernel chain)
  gemm_bt<1, 0, 0, 0, 0><<<dim3(6, 16, 1), blk, 0, stream>>>(
      oute_bf, Wattn_bf, nullptr, key_bf, nullptr,
      2048, 768, 768, 768, 768, 768, 0, 0, 0, BIGR, 0,
      nullptr, nullptr, 0);
  gemm_bt<0, 0, 0, 0, 0><<<dim3(3, 2, 8), blk, 0, stream>>>(
      key_bf, enc_bf, nullptr, scores, nullptr,
      256, 257, 768, 768, 768, 288, 196608L, 294912L, 73728L, BIGR, 0,
      nullptr, nullptr, 0);
  softmax_k<<<2048, blk, 0, stream>>>(scores, attn_bf);
  gemm_bt<1, 0, 0, 0, 0><<<dim3(6, 2, 8), blk, 0, stream>>>(
      attn_bf, encT_bf, nullptr, ctx_bf, nullptr,
      256, 768, 288, 288, 288, 768, 73728L, 221184L, 196608L, BIGR, 0,
      nullptr, nullptr, 0);

  // --- MLP GEMM with fused feature gather (replaces feat_k + MLP GEMM)
  gemm_mlp<<<dim3(6, 16), blk, 0, stream>>>(
      oute_bf, ctx_bf, enc_bf, outw_bf, ki_bt, an_bt,
      Wmlp_bf, b_mlp, mlp_bf);

  // SWAPXY: M-tiles on fast axis -> each Wout column-slab reused 16x from L2
  gemm_bt<0, 0, 0, 1, 1><<<dim3(16, 166, 1), blk, 0, stream>>>(
      mlp_bf, Wout_bf, b_out, out, nullptr,
      2040, 21128, 768, 768, 768, 21128, 0, 0, 0, BIGR, 0,
      nullptr, nullptr, 0);

  // --- fused log_softmax (in place)
  logsoftmax_k<<<2040, blk, 0, stream>>>(out);
}